// Round 8
// baseline (110.919 us; speedup 1.0000x reference)
//
#include <hip/hip_runtime.h>
#include <hip/hip_bf16.h>

#define NNODES 100000
#define NEDGES 1600000
#define IN_C   256
#define OUT_C  128

typedef short bf16x8 __attribute__((ext_vector_type(8)));
typedef float f32x4  __attribute__((ext_vector_type(4)));
typedef unsigned int u32x4 __attribute__((ext_vector_type(4)));

static __device__ __forceinline__ unsigned short f2bf(float f) {
    union { float f; unsigned u; } c; c.f = f;
    unsigned r = c.u + 0x7fffu + ((c.u >> 16) & 1u);   // round-to-nearest-even
    return (unsigned short)(r >> 16);
}
static __device__ __forceinline__ float bflo(unsigned u) {
    union { unsigned u; float f; } c; c.u = u << 16; return c.f;
}
static __device__ __forceinline__ float bfhi(unsigned u) {
    union { unsigned u; float f; } c; c.u = u & 0xffff0000u; return c.f;
}

union BF8 { bf16x8 v; unsigned short s[8]; };

// ---------------------------------------------------------------------------
// GEMM: H(bf16) = X @ W^T.  (round-4 structure + NT X loads)
// W staged once into 64KB XOR-swizzled LDS; X loaded directly into MFMA
// A-fragments from global with NON-TEMPORAL loads (X is single-use; keep it
// out of L3 so H/cols/vals stay resident for the spmm).
// ---------------------------------------------------------------------------
__global__ __launch_bounds__(512, 4) void gemm_xwt(const float* __restrict__ X,
                                                   const float* __restrict__ W,
                                                   unsigned short* __restrict__ H) {
    __shared__ unsigned short Wsh[128 * 256];   // bf16 bits, [n][k], swizzled, 64KB

    const int tid  = threadIdx.x;
    const int lane = tid & 63;
    const int wid  = tid >> 6;                  // 0..7

#pragma unroll
    for (int p = 0; p < 16; ++p) {
        int idx = p * 512 + tid;                // 0..8191 float4 index
        int n   = idx >> 6;                     // 0..127
        int c4  = idx & 63;                     // float4 column
        float4 v = *(const float4*)(W + (size_t)n * IN_C + c4 * 4);
        int byte = (n * 512 + c4 * 8) ^ ((n & 7) << 4);
        *(ushort4*)((char*)Wsh + byte) =
            make_ushort4(f2bf(v.x), f2bf(v.y), f2bf(v.z), f2bf(v.w));
    }
    __syncthreads();

    const int r0   = blockIdx.x * 128 + wid * 16;
    int arow = r0 + (lane & 15);
    if (arow > NNODES - 1) arow = NNODES - 1;   // clamp (tail rows discarded)
    const float* xrow = X + (size_t)arow * IN_C + (lane >> 4) * 8;

    f32x4 acc[8] = {};
#pragma unroll
    for (int ks = 0; ks < 8; ++ks) {
        f32x4 a0 = __builtin_nontemporal_load((const f32x4*)(xrow + ks * 32));
        f32x4 a1 = __builtin_nontemporal_load((const f32x4*)(xrow + ks * 32 + 4));
        BF8 t;
        t.s[0] = f2bf(a0[0]); t.s[1] = f2bf(a0[1]); t.s[2] = f2bf(a0[2]); t.s[3] = f2bf(a0[3]);
        t.s[4] = f2bf(a1[0]); t.s[5] = f2bf(a1[1]); t.s[6] = f2bf(a1[2]); t.s[7] = f2bf(a1[3]);
        const int kb = ks * 64 + (lane >> 4) * 16;      // byte offset in W row
#pragma unroll
        for (int n8 = 0; n8 < 8; ++n8) {
            int nr   = n8 * 16 + (lane & 15);
            int byte = (nr * 512 + kb) ^ ((nr & 7) << 4);
            bf16x8 b = *(const bf16x8*)((const char*)Wsh + byte);
            acc[n8] = __builtin_amdgcn_mfma_f32_16x16x32_bf16(t.v, b, acc[n8],
                                                              0, 0, 0);
        }
    }

    // H stays cacheable (spmm reads it next) — normal stores.
#pragma unroll
    for (int n8 = 0; n8 < 8; ++n8) {
#pragma unroll
        for (int r = 0; r < 4; ++r) {
            int grow = r0 + (lane >> 4) * 4 + r;
            if (grow < NNODES)
                H[(size_t)grow * OUT_C + n8 * 16 + (lane & 15)] = f2bf(acc[n8][r]);
        }
    }
}

// ---------------------------------------------------------------------------
// rowptr[r] = lower_bound(A_rows, r)  (A_rows sorted).  r in [0, N].
// ---------------------------------------------------------------------------
__global__ __launch_bounds__(256) void build_rowptr(const int* __restrict__ rows,
                                                    int* __restrict__ rowptr) {
    int r = blockIdx.x * 256 + threadIdx.x;
    if (r > NNODES) return;
    int lo = 0, hi = NEDGES;
    while (lo < hi) {
        int mid = (lo + hi) >> 1;
        if (rows[mid] < r) lo = mid + 1; else hi = mid;
    }
    rowptr[r] = lo;
}

// ---------------------------------------------------------------------------
// SpMM: out[r,:] = sum_e vals[e] * H[cols[e],:].  One wave per row.
// (round-5 structure, best measured: 16 lanes/edge, uint4 gathers, 16-edge
// unroll)  +  NON-TEMPORAL out stores (out is never re-read; keep it out of
// L3 so H stays resident).
// ---------------------------------------------------------------------------
__global__ __launch_bounds__(256) void spmm_rows(const uint4* __restrict__ H4,
                                                 const int* __restrict__ rowptr,
                                                 const int* __restrict__ cols,
                                                 const float* __restrict__ vals,
                                                 float* __restrict__ out) {
    const int wid  = threadIdx.x >> 6;
    const int lane = threadIdx.x & 63;
    const int row  = blockIdx.x * 4 + wid;
    if (row >= NNODES) return;

    const int s  = rowptr[row];
    const int e  = rowptr[row + 1];
    const int g  = lane >> 4;      // edge subgroup 0..3
    const int cg = lane & 15;      // channel group: channels cg*8 .. cg*8+7

    float acc[8];
#pragma unroll
    for (int t = 0; t < 8; ++t) acc[t] = 0.f;

    for (int base = s; base < e; base += 64) {
        const int cnt = (e - base < 64) ? (e - base) : 64;
        int   ec = 0;
        float ev = 0.f;
        if (lane < cnt) { ec = cols[base + lane]; ev = vals[base + lane]; }

        int j = 0;
        // main: 16 edges per iteration -> 4 independent 16B gathers in flight
        for (; j + 16 <= cnt; j += 16) {
#pragma unroll
            for (int q = 0; q < 4; ++q) {
                int   c = __shfl(ec, j + q * 4 + g);
                float v = __shfl(ev, j + q * 4 + g);
                uint4 u = H4[(size_t)c * 16 + cg];
                acc[0] += v * bflo(u.x); acc[1] += v * bfhi(u.x);
                acc[2] += v * bflo(u.y); acc[3] += v * bfhi(u.y);
                acc[4] += v * bflo(u.z); acc[5] += v * bfhi(u.z);
                acc[6] += v * bflo(u.w); acc[7] += v * bfhi(u.w);
            }
        }
        // tail: 4 edges at a time (overshoot lanes have ev=0 -> contribute 0)
        for (; j < cnt; j += 4) {
            int   c = __shfl(ec, j + g);
            float v = __shfl(ev, j + g);
            uint4 u = H4[(size_t)c * 16 + cg];
            acc[0] += v * bflo(u.x); acc[1] += v * bfhi(u.x);
            acc[2] += v * bflo(u.y); acc[3] += v * bfhi(u.y);
            acc[4] += v * bflo(u.z); acc[5] += v * bfhi(u.z);
            acc[6] += v * bflo(u.w); acc[7] += v * bfhi(u.w);
        }
    }

    // reduce across the 4 edge subgroups (lanes cg, cg+16, cg+32, cg+48)
#pragma unroll
    for (int t = 0; t < 8; ++t) {
        acc[t] += __shfl_xor(acc[t], 16);
        acc[t] += __shfl_xor(acc[t], 32);
    }
    if (lane < 16) {
        f32x4 v0 = { acc[0], acc[1], acc[2], acc[3] };
        f32x4 v1 = { acc[4], acc[5], acc[6], acc[7] };
        __builtin_nontemporal_store(v0, (f32x4*)(out + (size_t)row * OUT_C + cg * 8));
        __builtin_nontemporal_store(v1, (f32x4*)(out + (size_t)row * OUT_C + cg * 8 + 4));
    }
}

// ---------------------------------------------------------------------------
extern "C" void kernel_launch(void* const* d_in, const int* in_sizes, int n_in,
                              void* d_out, int out_size, void* d_ws, size_t ws_size,
                              hipStream_t stream) {
    const float* X      = (const float*)d_in[0];
    const float* W      = (const float*)d_in[1];
    const int*   A_rows = (const int*)d_in[2];
    const int*   A_cols = (const int*)d_in[3];
    const float* A_vals = (const float*)d_in[4];
    float* out = (float*)d_out;

    unsigned short* H   = (unsigned short*)d_ws;                    // 25.6 MB bf16
    int* rowptr = (int*)((char*)d_ws +
                         (size_t)NNODES * OUT_C * sizeof(unsigned short));

    gemm_xwt<<<(NNODES + 127) / 128, 512, 0, stream>>>(X, W, H);
    build_rowptr<<<(NNODES + 1 + 255) / 256, 256, 0, stream>>>(A_rows, rowptr);
    spmm_rows<<<(NNODES + 3) / 4, 256, 0, stream>>>((const uint4*)H, rowptr,
                                                    A_cols, A_vals, out);
}

// Round 9
// 92.153 us; speedup vs baseline: 1.2036x; 1.2036x over previous
//
#include <hip/hip_runtime.h>
#include <hip/hip_bf16.h>

#define NNODES 100000
#define NEDGES 1600000
#define IN_C   256
#define OUT_C  128

typedef short bf16x8 __attribute__((ext_vector_type(8)));
typedef float f32x4  __attribute__((ext_vector_type(4)));

static __device__ __forceinline__ unsigned short f2bf(float f) {
    union { float f; unsigned u; } c; c.f = f;
    unsigned r = c.u + 0x7fffu + ((c.u >> 16) & 1u);   // round-to-nearest-even
    return (unsigned short)(r >> 16);
}

union BF8 { bf16x8 v; unsigned short s[8]; };

// ---------------------------------------------------------------------------
// GEMM: H(int8, per-row scale) = quant(X @ W^T).
// W staged once into 64KB XOR-swizzled LDS; X loaded directly into MFMA
// A-fragments from global (plain loads — NT was a measured regression).
// Epilogue: per-row amax (shfl_xor within 16-lane group) -> scale = amax/127,
// quantized byte stores (each 128B H-line fully covered by its wave).
// ---------------------------------------------------------------------------
__global__ __launch_bounds__(512, 4) void gemm_xwt(const float* __restrict__ X,
                                                   const float* __restrict__ W,
                                                   signed char* __restrict__ H8,
                                                   float* __restrict__ scale) {
    __shared__ unsigned short Wsh[128 * 256];   // bf16 bits, [n][k], swizzled, 64KB

    const int tid  = threadIdx.x;
    const int lane = tid & 63;
    const int wid  = tid >> 6;                  // 0..7

#pragma unroll
    for (int p = 0; p < 16; ++p) {
        int idx = p * 512 + tid;                // 0..8191 float4 index
        int n   = idx >> 6;                     // 0..127
        int c4  = idx & 63;                     // float4 column
        float4 v = *(const float4*)(W + (size_t)n * IN_C + c4 * 4);
        int byte = (n * 512 + c4 * 8) ^ ((n & 7) << 4);
        *(ushort4*)((char*)Wsh + byte) =
            make_ushort4(f2bf(v.x), f2bf(v.y), f2bf(v.z), f2bf(v.w));
    }
    __syncthreads();

    const int r0   = blockIdx.x * 128 + wid * 16;
    int arow = r0 + (lane & 15);
    if (arow > NNODES - 1) arow = NNODES - 1;   // clamp (tail rows discarded)
    const float* xrow = X + (size_t)arow * IN_C + (lane >> 4) * 8;

    f32x4 acc[8] = {};
#pragma unroll
    for (int ks = 0; ks < 8; ++ks) {
        float4 a0 = *(const float4*)(xrow + ks * 32);
        float4 a1 = *(const float4*)(xrow + ks * 32 + 4);
        BF8 t;
        t.s[0] = f2bf(a0.x); t.s[1] = f2bf(a0.y); t.s[2] = f2bf(a0.z); t.s[3] = f2bf(a0.w);
        t.s[4] = f2bf(a1.x); t.s[5] = f2bf(a1.y); t.s[6] = f2bf(a1.z); t.s[7] = f2bf(a1.w);
        const int kb = ks * 64 + (lane >> 4) * 16;      // byte offset in W row
#pragma unroll
        for (int n8 = 0; n8 < 8; ++n8) {
            int nr   = n8 * 16 + (lane & 15);
            int byte = (nr * 512 + kb) ^ ((nr & 7) << 4);
            bf16x8 b = *(const bf16x8*)((const char*)Wsh + byte);
            acc[n8] = __builtin_amdgcn_mfma_f32_16x16x32_bf16(t.v, b, acc[n8],
                                                              0, 0, 0);
        }
    }

    // --- epilogue: per-row amax -> int8 quantize ---
    // lane holds rows (lane>>4)*4+r (r=0..3), cols n8*16+(lane&15).
    float amax[4];
#pragma unroll
    for (int r = 0; r < 4; ++r) {
        float m = 0.f;
#pragma unroll
        for (int n8 = 0; n8 < 8; ++n8) m = fmaxf(m, fabsf(acc[n8][r]));
        amax[r] = m;
    }
#pragma unroll
    for (int d = 1; d < 16; d <<= 1)
#pragma unroll
        for (int r = 0; r < 4; ++r)
            amax[r] = fmaxf(amax[r], __shfl_xor(amax[r], d));

#pragma unroll
    for (int r = 0; r < 4; ++r) {
        int grow = r0 + (lane >> 4) * 4 + r;
        if (grow < NNODES) {
            float am  = amax[r];
            float inv = am > 0.f ? 127.f / am : 0.f;
            if ((lane & 15) == 0) scale[grow] = am * (1.f / 127.f);
#pragma unroll
            for (int n8 = 0; n8 < 8; ++n8) {
                float q = rintf(acc[n8][r] * inv);
                q = fminf(127.f, fmaxf(-127.f, q));
                H8[(size_t)grow * OUT_C + n8 * 16 + (lane & 15)] = (signed char)q;
            }
        }
    }
}

// ---------------------------------------------------------------------------
// rowptr[r] = lower_bound(A_rows, r)  (A_rows sorted).  r in [0, N].
// ---------------------------------------------------------------------------
__global__ __launch_bounds__(256) void build_rowptr(const int* __restrict__ rows,
                                                    int* __restrict__ rowptr) {
    int r = blockIdx.x * 256 + threadIdx.x;
    if (r > NNODES) return;
    int lo = 0, hi = NEDGES;
    while (lo < hi) {
        int mid = (lo + hi) >> 1;
        if (rows[mid] < r) lo = mid + 1; else hi = mid;
    }
    rowptr[r] = lo;
}

// ---------------------------------------------------------------------------
// SpMM: out[r,:] = sum_e vals[e]*scale[c_e] * H8[c_e,:].  One wave per row.
// int8 H: row = 128 B = ONE cache line; lane gathers uint2 (8 channels).
// scale[c] folded into ev at the cols/vals preload. 16 lanes/edge, 4 edges
// per instruction, 16-edge unroll -> 4 gathers in flight. NT out stores.
// ---------------------------------------------------------------------------
__global__ __launch_bounds__(256) void spmm_rows(const uint2* __restrict__ H2,
                                                 const int* __restrict__ rowptr,
                                                 const int* __restrict__ cols,
                                                 const float* __restrict__ vals,
                                                 const float* __restrict__ scale,
                                                 float* __restrict__ out) {
    const int wid  = threadIdx.x >> 6;
    const int lane = threadIdx.x & 63;
    const int row  = blockIdx.x * 4 + wid;
    if (row >= NNODES) return;

    const int s  = rowptr[row];
    const int e  = rowptr[row + 1];
    const int g  = lane >> 4;      // edge subgroup 0..3
    const int cg = lane & 15;      // channel group: channels cg*8 .. cg*8+7

    float acc[8];
#pragma unroll
    for (int t = 0; t < 8; ++t) acc[t] = 0.f;

    for (int base = s; base < e; base += 64) {
        const int cnt = (e - base < 64) ? (e - base) : 64;
        int   ec = 0;
        float ev = 0.f;
        if (lane < cnt) {
            ec = cols[base + lane];
            ev = vals[base + lane] * scale[ec];
        }

        int j = 0;
        for (; j + 16 <= cnt; j += 16) {
#pragma unroll
            for (int q = 0; q < 4; ++q) {
                int   c = __shfl(ec, j + q * 4 + g);
                float v = __shfl(ev, j + q * 4 + g);
                uint2 u = H2[(size_t)c * 16 + cg];
                acc[0] += v * (float)(signed char)(u.x);
                acc[1] += v * (float)(signed char)(u.x >> 8);
                acc[2] += v * (float)(signed char)(u.x >> 16);
                acc[3] += v * (float)(signed char)(u.x >> 24);
                acc[4] += v * (float)(signed char)(u.y);
                acc[5] += v * (float)(signed char)(u.y >> 8);
                acc[6] += v * (float)(signed char)(u.y >> 16);
                acc[7] += v * (float)(signed char)(u.y >> 24);
            }
        }
        for (; j < cnt; j += 4) {
            int   c = __shfl(ec, j + g);
            float v = __shfl(ev, j + g);
            uint2 u = H2[(size_t)c * 16 + cg];
            acc[0] += v * (float)(signed char)(u.x);
            acc[1] += v * (float)(signed char)(u.x >> 8);
            acc[2] += v * (float)(signed char)(u.x >> 16);
            acc[3] += v * (float)(signed char)(u.x >> 24);
            acc[4] += v * (float)(signed char)(u.y);
            acc[5] += v * (float)(signed char)(u.y >> 8);
            acc[6] += v * (float)(signed char)(u.y >> 16);
            acc[7] += v * (float)(signed char)(u.y >> 24);
        }
    }

#pragma unroll
    for (int t = 0; t < 8; ++t) {
        acc[t] += __shfl_xor(acc[t], 16);
        acc[t] += __shfl_xor(acc[t], 32);
    }
    if (lane < 16) {
        f32x4 v0 = { acc[0], acc[1], acc[2], acc[3] };
        f32x4 v1 = { acc[4], acc[5], acc[6], acc[7] };
        __builtin_nontemporal_store(v0, (f32x4*)(out + (size_t)row * OUT_C + cg * 8));
        __builtin_nontemporal_store(v1, (f32x4*)(out + (size_t)row * OUT_C + cg * 8 + 4));
    }
}

// ---------------------------------------------------------------------------
extern "C" void kernel_launch(void* const* d_in, const int* in_sizes, int n_in,
                              void* d_out, int out_size, void* d_ws, size_t ws_size,
                              hipStream_t stream) {
    const float* X      = (const float*)d_in[0];
    const float* W      = (const float*)d_in[1];
    const int*   A_rows = (const int*)d_in[2];
    const int*   A_cols = (const int*)d_in[3];
    const float* A_vals = (const float*)d_in[4];
    float* out = (float*)d_out;

    signed char* H8    = (signed char*)d_ws;                         // 12.8 MB
    float*       scale = (float*)((char*)d_ws + (size_t)NNODES * OUT_C);   // 400 KB
    int*         rowptr = (int*)((char*)scale + (size_t)NNODES * sizeof(float));

    gemm_xwt<<<(NNODES + 127) / 128, 512, 0, stream>>>(X, W, H8, scale);
    build_rowptr<<<(NNODES + 1 + 255) / 256, 256, 0, stream>>>(A_rows, rowptr);
    spmm_rows<<<(NNODES + 3) / 4, 256, 0, stream>>>((const uint2*)H8, rowptr,
                                                    A_cols, A_vals, scale, out);
}

// Round 10
// 91.871 us; speedup vs baseline: 1.2073x; 1.0031x over previous
//
#include <hip/hip_runtime.h>
#include <hip/hip_bf16.h>

#define NNODES 100000
#define NEDGES 1600000
#define IN_C   256
#define OUT_C  128

typedef short bf16x8 __attribute__((ext_vector_type(8)));
typedef float f32x4  __attribute__((ext_vector_type(4)));

static __device__ __forceinline__ unsigned short f2bf(float f) {
    union { float f; unsigned u; } c; c.f = f;
    unsigned r = c.u + 0x7fffu + ((c.u >> 16) & 1u);   // round-to-nearest-even
    return (unsigned short)(r >> 16);
}

union BF8 { bf16x8 v; unsigned short s[8]; };

// ---------------------------------------------------------------------------
// GEMM: H(int8, per-row scale) = quant(X @ W^T).   (unchanged from round 9)
// ---------------------------------------------------------------------------
__global__ __launch_bounds__(512, 4) void gemm_xwt(const float* __restrict__ X,
                                                   const float* __restrict__ W,
                                                   signed char* __restrict__ H8,
                                                   float* __restrict__ scale) {
    __shared__ unsigned short Wsh[128 * 256];   // bf16 bits, [n][k], swizzled, 64KB

    const int tid  = threadIdx.x;
    const int lane = tid & 63;
    const int wid  = tid >> 6;                  // 0..7

#pragma unroll
    for (int p = 0; p < 16; ++p) {
        int idx = p * 512 + tid;                // 0..8191 float4 index
        int n   = idx >> 6;                     // 0..127
        int c4  = idx & 63;                     // float4 column
        float4 v = *(const float4*)(W + (size_t)n * IN_C + c4 * 4);
        int byte = (n * 512 + c4 * 8) ^ ((n & 7) << 4);
        *(ushort4*)((char*)Wsh + byte) =
            make_ushort4(f2bf(v.x), f2bf(v.y), f2bf(v.z), f2bf(v.w));
    }
    __syncthreads();

    const int r0   = blockIdx.x * 128 + wid * 16;
    int arow = r0 + (lane & 15);
    if (arow > NNODES - 1) arow = NNODES - 1;   // clamp (tail rows discarded)
    const float* xrow = X + (size_t)arow * IN_C + (lane >> 4) * 8;

    f32x4 acc[8] = {};
#pragma unroll
    for (int ks = 0; ks < 8; ++ks) {
        float4 a0 = *(const float4*)(xrow + ks * 32);
        float4 a1 = *(const float4*)(xrow + ks * 32 + 4);
        BF8 t;
        t.s[0] = f2bf(a0.x); t.s[1] = f2bf(a0.y); t.s[2] = f2bf(a0.z); t.s[3] = f2bf(a0.w);
        t.s[4] = f2bf(a1.x); t.s[5] = f2bf(a1.y); t.s[6] = f2bf(a1.z); t.s[7] = f2bf(a1.w);
        const int kb = ks * 64 + (lane >> 4) * 16;      // byte offset in W row
#pragma unroll
        for (int n8 = 0; n8 < 8; ++n8) {
            int nr   = n8 * 16 + (lane & 15);
            int byte = (nr * 512 + kb) ^ ((nr & 7) << 4);
            bf16x8 b = *(const bf16x8*)((const char*)Wsh + byte);
            acc[n8] = __builtin_amdgcn_mfma_f32_16x16x32_bf16(t.v, b, acc[n8],
                                                              0, 0, 0);
        }
    }

    // --- epilogue: per-row amax -> int8 quantize ---
    float amax[4];
#pragma unroll
    for (int r = 0; r < 4; ++r) {
        float m = 0.f;
#pragma unroll
        for (int n8 = 0; n8 < 8; ++n8) m = fmaxf(m, fabsf(acc[n8][r]));
        amax[r] = m;
    }
#pragma unroll
    for (int d = 1; d < 16; d <<= 1)
#pragma unroll
        for (int r = 0; r < 4; ++r)
            amax[r] = fmaxf(amax[r], __shfl_xor(amax[r], d));

#pragma unroll
    for (int r = 0; r < 4; ++r) {
        int grow = r0 + (lane >> 4) * 4 + r;
        if (grow < NNODES) {
            float am  = amax[r];
            float inv = am > 0.f ? 127.f / am : 0.f;
            if ((lane & 15) == 0) scale[grow] = am * (1.f / 127.f);
#pragma unroll
            for (int n8 = 0; n8 < 8; ++n8) {
                float q = rintf(acc[n8][r] * inv);
                q = fminf(127.f, fmaxf(-127.f, q));
                H8[(size_t)grow * OUT_C + n8 * 16 + (lane & 15)] = (signed char)q;
            }
        }
    }
}

// ---------------------------------------------------------------------------
// rowptr[r] = lower_bound(A_rows, r)  (A_rows sorted).  r in [0, N].
// ---------------------------------------------------------------------------
__global__ __launch_bounds__(256) void build_rowptr(const int* __restrict__ rows,
                                                    int* __restrict__ rowptr) {
    int r = blockIdx.x * 256 + threadIdx.x;
    if (r > NNODES) return;
    int lo = 0, hi = NEDGES;
    while (lo < hi) {
        int mid = (lo + hi) >> 1;
        if (rows[mid] < r) lo = mid + 1; else hi = mid;
    }
    rowptr[r] = lo;
}

// ---------------------------------------------------------------------------
// SpMM: out[r,:] = sum_e vals[e]*scale[c_e] * H8[c_e,:].
// TWO rows per wave, software-pipelined: independent register state per row;
// the two rows' load->shfl->gather->FMA chains interleave, halving effective
// per-row serial latency and keeping 8 gathers in flight per wave.
// All control branches are wave-uniform. 16 lanes/edge, uint2 (8 ch) gathers.
// ---------------------------------------------------------------------------
static __device__ __forceinline__ void edge4(float acc[8], int ec, float ev,
                                             int jg, const uint2* __restrict__ H2,
                                             int cg) {
    int   c = __shfl(ec, jg);
    float v = __shfl(ev, jg);
    uint2 u = H2[(size_t)c * 16 + cg];
    acc[0] += v * (float)(signed char)(u.x);
    acc[1] += v * (float)(signed char)(u.x >> 8);
    acc[2] += v * (float)(signed char)(u.x >> 16);
    acc[3] += v * (float)(signed char)(u.x >> 24);
    acc[4] += v * (float)(signed char)(u.y);
    acc[5] += v * (float)(signed char)(u.y >> 8);
    acc[6] += v * (float)(signed char)(u.y >> 16);
    acc[7] += v * (float)(signed char)(u.y >> 24);
}

__global__ __launch_bounds__(256) void spmm_rows(const uint2* __restrict__ H2,
                                                 const int* __restrict__ rowptr,
                                                 const int* __restrict__ cols,
                                                 const float* __restrict__ vals,
                                                 const float* __restrict__ scale,
                                                 float* __restrict__ out) {
    const int wid  = threadIdx.x >> 6;
    const int lane = threadIdx.x & 63;
    const int g    = lane >> 4;      // edge subgroup 0..3
    const int cg   = lane & 15;      // channel group: channels cg*8 .. cg*8+7

    const int rowA = (blockIdx.x * 4 + wid) * 2;   // rowB = rowA + 1
    const int sA = rowptr[rowA];
    const int eA = rowptr[rowA + 1];
    const int eB = rowptr[rowA + 2];

    float accA[8], accB[8];
#pragma unroll
    for (int t = 0; t < 8; ++t) { accA[t] = 0.f; accB[t] = 0.f; }

    int baseA = sA, baseB = eA;
    while (baseA < eA || baseB < eB) {
        int cntA = eA - baseA; cntA = cntA < 0 ? 0 : (cntA > 64 ? 64 : cntA);
        int cntB = eB - baseB; cntB = cntB < 0 ? 0 : (cntB > 64 ? 64 : cntB);

        int   ecA = 0, ecB = 0;
        float evA = 0.f, evB = 0.f;
        if (lane < cntA) { ecA = cols[baseA + lane]; evA = vals[baseA + lane] * scale[ecA]; }
        if (lane < cntB) { ecB = cols[baseB + lane]; evB = vals[baseB + lane] * scale[ecB]; }

        const int mx = cntA > cntB ? cntA : cntB;
        for (int j = 0; j < mx; j += 8) {
            // wave-uniform guards; overshoot lanes inside a live group have
            // ev=0 -> contribute 0 (gather of H2 row 0 line, L2-hit).
            if (j < cntA)     edge4(accA, ecA, evA, j + g,     H2, cg);
            if (j < cntB)     edge4(accB, ecB, evB, j + g,     H2, cg);
            if (j + 4 < cntA) edge4(accA, ecA, evA, j + 4 + g, H2, cg);
            if (j + 4 < cntB) edge4(accB, ecB, evB, j + 4 + g, H2, cg);
        }

        baseA += cntA;
        baseB += cntB;
    }

    // reduce across the 4 edge subgroups
#pragma unroll
    for (int t = 0; t < 8; ++t) {
        accA[t] += __shfl_xor(accA[t], 16);
        accA[t] += __shfl_xor(accA[t], 32);
        accB[t] += __shfl_xor(accB[t], 16);
        accB[t] += __shfl_xor(accB[t], 32);
    }
    if (lane < 16) {
        f32x4 a0 = { accA[0], accA[1], accA[2], accA[3] };
        f32x4 a1 = { accA[4], accA[5], accA[6], accA[7] };
        f32x4 b0 = { accB[0], accB[1], accB[2], accB[3] };
        f32x4 b1 = { accB[4], accB[5], accB[6], accB[7] };
        __builtin_nontemporal_store(a0, (f32x4*)(out + (size_t)rowA * OUT_C + cg * 8));
        __builtin_nontemporal_store(a1, (f32x4*)(out + (size_t)rowA * OUT_C + cg * 8 + 4));
        __builtin_nontemporal_store(b0, (f32x4*)(out + (size_t)(rowA + 1) * OUT_C + cg * 8));
        __builtin_nontemporal_store(b1, (f32x4*)(out + (size_t)(rowA + 1) * OUT_C + cg * 8 + 4));
    }
}

// ---------------------------------------------------------------------------
extern "C" void kernel_launch(void* const* d_in, const int* in_sizes, int n_in,
                              void* d_out, int out_size, void* d_ws, size_t ws_size,
                              hipStream_t stream) {
    const float* X      = (const float*)d_in[0];
    const float* W      = (const float*)d_in[1];
    const int*   A_rows = (const int*)d_in[2];
    const int*   A_cols = (const int*)d_in[3];
    const float* A_vals = (const float*)d_in[4];
    float* out = (float*)d_out;

    signed char* H8    = (signed char*)d_ws;                         // 12.8 MB
    float*       scale = (float*)((char*)d_ws + (size_t)NNODES * OUT_C);   // 400 KB
    int*         rowptr = (int*)((char*)scale + (size_t)NNODES * sizeof(float));

    gemm_xwt<<<(NNODES + 127) / 128, 512, 0, stream>>>(X, W, H8, scale);
    build_rowptr<<<(NNODES + 1 + 255) / 256, 256, 0, stream>>>(A_rows, rowptr);
    spmm_rows<<<(NNODES + 7) / 8, 256, 0, stream>>>((const uint2*)H8, rowptr,
                                                    A_cols, A_vals, scale, out);
}